// Round 4
// baseline (53.583 us; speedup 1.0000x reference)
//
#include <hip/hip_runtime.h>
#include <hip/hip_bf16.h>

// ShuffleNet fused block-MLP, MI355X (gfx950).  R4: barrier-free 2-kernel split.
// x:(8192,1024) f32; w1:(16,256,64); b1:(4096); w2:(16,64,256); b2:(1024); y f32.
//   h[b,n,o] = sum_i x[b,n*64+i]*w1[n,o,i];  shuffled j = o*16+n
//   g = gelu(h+b1);  y[b,n'*64+o'] = sum_{i'} g[b,n'*256+i']*w2[n',o',i'] + b2
//   i' (chunk order used here) = n*16 + ohi, o = np*16 + ohi.
// K1: x -> g, written to ws in K2's exact A-fragment order (no LDS, no barrier).
// K2: g -> y, pure streaming MFMA (no LDS, no barrier).
// G layout (shorts): G[rt][np][n][row16][ohi16]; strides 65536/4096/256/16/1.
//   K1 lane(l15,lhi) stores 4 shorts at [n][l15][lhi*4]  (ohi = lhi*4+r).
//   K2 lane(l15,lhi) ks reads 8 shorts at [2ks+(lhi>>1)][l15][(lhi&1)*8].
// ws: w1p 512KB + w2p 512KB + b1p 256KB + G 64MB  (needs ws_size >= ~65.3MB).

typedef __attribute__((ext_vector_type(8))) short  short8;   // 8 bf16 = 4 VGPR
typedef __attribute__((ext_vector_type(4))) short  short4v;
typedef __attribute__((ext_vector_type(4))) float  floatx4;

__device__ __forceinline__ short f2bf(float f) {
  union { __hip_bfloat16 h; short s; } u;
  u.h = __float2bfloat16(f);
  return u.s;
}

// gelu(v) ~= v * sigmoid(1.5957691*(v + 0.044715 v^3)) (abs err < 5e-4)
__device__ __forceinline__ float gelu_f(float v) {
  float v2 = v * v;
  float p  = fmaf(0.044715f, v2, 1.0f);
  float t  = v * p;
  float e  = __expf(-1.5957691f * t);
  return v * __builtin_amdgcn_rcpf(1.0f + e);
}

// ---- one pack kernel: w1 frags | w2 frags | b1 frags ----
// w1 frag (n,np,ks): lane l elem e = w1[n][np*16+(l&15)][ks*32+(l>>4)*8+e]
// w2 frag (np,ks,ot): lane l elem e: k=ks*32+(l>>4)*8+e; n=k>>4; ohi=k&15;
//                     value = w2[np][ot*16+(l&15)][ohi*16+n]
// b1 frag (n,np): lane l reg r = b1[(np*16+(l>>4)*4+r)*16+n]
__global__ void pack_k(const float* __restrict__ w1, const float* __restrict__ w2,
                       const float* __restrict__ b1, short* __restrict__ w1p,
                       short* __restrict__ w2p, float* __restrict__ b1p) {
  const int t = blockIdx.x * blockDim.x + threadIdx.x;  // 160*512 = 81920
  const int lane = t & 63;
  const int lhi = lane >> 4;
  if (t < 32768) {  // w1
    const int ks = (t >> 6) & 1, np = (t >> 7) & 15, n = (t >> 11) & 15;
    const float* src = w1 + ((size_t)(n * 256 + np * 16 + (lane & 15)) * 64 + ks * 32 + lhi * 8);
    short8 f;
#pragma unroll
    for (int e = 0; e < 8; ++e) f[e] = f2bf(src[e]);
    *(short8*)(w1p + (size_t)t * 8) = f;
  } else if (t < 65536) {  // w2
    const int t2 = t - 32768;
    const int ot = (t2 >> 6) & 3, ks = (t2 >> 8) & 7, np = (t2 >> 11) & 15;
    const int op = ot * 16 + (lane & 15);
    short8 f;
#pragma unroll
    for (int e = 0; e < 8; ++e) {
      const int k = ks * 32 + lhi * 8 + e;
      f[e] = f2bf(w2[(size_t)(np * 64 + op) * 256 + (k & 15) * 16 + (k >> 4)]);
    }
    *(short8*)(w2p + (size_t)t2 * 8) = f;
  } else {  // b1
    const int t3 = t - 65536;  // 16384
    const int np = (t3 >> 6) & 15, n = (t3 >> 10) & 15;
    floatx4 b;
#pragma unroll
    for (int r = 0; r < 4; ++r) b[r] = b1[(np * 16 + lhi * 4 + r) * 16 + n];
    *(floatx4*)(b1p + (size_t)((n * 16 + np) * 64 + lane) * 4) = b;
  }
}

// ---- K1: x -> g (packed), 2048 WGs x 256 thr, wave = (rt, n) ----
__global__ __launch_bounds__(256, 4) void k1_gemm1(
    const float* __restrict__ x, const short* __restrict__ w1p,
    const float* __restrict__ b1p, short* __restrict__ G) {
  const int tid = threadIdx.x;
  const int wv = tid >> 6, lane = tid & 63;
  const int l15 = lane & 15, lhi = lane >> 4;
  const int rt = blockIdx.x >> 2;
  const int n  = (blockIdx.x & 3) * 4 + wv;

  // x fragments (B-operand: col = l15 = row, k = lhi*8+e contiguous)
  short8 xf[2];
#pragma unroll
  for (int ks = 0; ks < 2; ++ks) {
    const float* px = x + (size_t)(rt * 16 + l15) * 1024 + n * 64 + ks * 32 + lhi * 8;
    floatx4 a = *(const floatx4*)px;
    floatx4 b = *(const floatx4*)(px + 4);
    short8 f;
#pragma unroll
    for (int e = 0; e < 4; ++e) { f[e] = f2bf(a[e]); f[e + 4] = f2bf(b[e]); }
    xf[ks] = f;
  }

  short* gbase = G + (size_t)rt * 65536 + n * 256 + l15 * 16 + lhi * 4;
#pragma unroll
  for (int np = 0; np < 16; ++np) {
    short8 wf0 = *(const short8*)(w1p + (size_t)(((n * 16 + np) * 2 + 0) * 64 + lane) * 8);
    short8 wf1 = *(const short8*)(w1p + (size_t)(((n * 16 + np) * 2 + 1) * 64 + lane) * 8);
    floatx4 bias = *(const floatx4*)(b1p + (size_t)((n * 16 + np) * 64 + lane) * 4);
    floatx4 acc = {0.f, 0.f, 0.f, 0.f};
    acc = __builtin_amdgcn_mfma_f32_16x16x32_bf16(wf0, xf[0], acc, 0, 0, 0);
    acc = __builtin_amdgcn_mfma_f32_16x16x32_bf16(wf1, xf[1], acc, 0, 0, 0);
    short4v hv;
#pragma unroll
    for (int r = 0; r < 4; ++r)
      hv[r] = f2bf(gelu_f(acc[r] + bias[r]));
    *(short4v*)(gbase + (size_t)np * 4096) = hv;   // 64 lanes -> 512B contiguous
  }
}

// ---- K2: g -> y, 2048 WGs x 256 thr, wave = (rt, np) ----
__global__ __launch_bounds__(256, 4) void k2_gemm2(
    const short* __restrict__ G, const short* __restrict__ w2p,
    const float* __restrict__ b2, float* __restrict__ y) {
  const int tid = threadIdx.x;
  const int wv = tid >> 6, lane = tid & 63;
  const int l15 = lane & 15, lhi = lane >> 4;
  const int rt = blockIdx.x >> 2;
  const int np = (blockIdx.x & 3) * 4 + wv;

  // A-frags: lane holds row = l15, k = ks*32+lhi*8+e (chunk order n*16+ohi)
  const short* ab = G + (size_t)(rt * 16 + np) * 4096 + (lhi >> 1) * 256 + l15 * 16 + (lhi & 1) * 8;
  short8 af[8];
#pragma unroll
  for (int ks = 0; ks < 8; ++ks)
    af[ks] = *(const short8*)(ab + ks * 512);

#pragma unroll
  for (int ot = 0; ot < 4; ++ot) {
    floatx4 a0 = {0.f, 0.f, 0.f, 0.f}, a1 = {0.f, 0.f, 0.f, 0.f};
#pragma unroll
    for (int ks = 0; ks < 8; ks += 2) {
      short8 b0 = *(const short8*)(w2p + (size_t)(((np * 8 + ks) * 4 + ot) * 64 + lane) * 8);
      short8 b1f = *(const short8*)(w2p + (size_t)(((np * 8 + ks + 1) * 4 + ot) * 64 + lane) * 8);
      a0 = __builtin_amdgcn_mfma_f32_16x16x32_bf16(af[ks], b0, a0, 0, 0, 0);
      a1 = __builtin_amdgcn_mfma_f32_16x16x32_bf16(af[ks + 1], b1f, a1, 0, 0, 0);
    }
    const int col = np * 64 + ot * 16 + l15;
    const float bb = b2[col];
    float* py = y + (size_t)(rt * 16 + lhi * 4) * 1024 + col;
#pragma unroll
    for (int r = 0; r < 4; ++r)
      py[(size_t)r * 1024] = a0[r] + a1[r] + bb;
  }
}

extern "C" void kernel_launch(void* const* d_in, const int* in_sizes, int n_in,
                              void* d_out, int out_size, void* d_ws, size_t ws_size,
                              hipStream_t stream) {
  const float* x  = (const float*)d_in[0];
  const float* w1 = (const float*)d_in[1];
  const float* b1 = (const float*)d_in[2];
  const float* w2 = (const float*)d_in[3];
  const float* b2 = (const float*)d_in[4];
  float* y = (float*)d_out;

  short* w1p = (short*)d_ws;               // 512 KB
  short* w2p = w1p + 16 * 256 * 64;        // 512 KB
  float* b1p = (float*)(w2p + 16 * 256 * 64);  // 256 KB
  short* G   = (short*)(b1p + 16 * 16 * 64 * 4);  // 64 MB

  pack_k<<<160, 512, 0, stream>>>(w1, w2, b1, w1p, w2p, b1p);
  k1_gemm1<<<2048, 256, 0, stream>>>(x, w1p, b1p, G);
  k2_gemm2<<<2048, 256, 0, stream>>>(G, w2p, b2, y);
}